// Round 7
// baseline (206.031 us; speedup 1.0000x reference)
//
#include <hip/hip_runtime.h>

// DWT roundtrip, algebraically simplified and fused (one kernel, no workspace):
//   out = haar_idwt2(aa1, U(lh1), U(hl1), U(hh1)),  U = cubic_up2 . area_down2
// (level-2 encode/decode cancels; validated rounds 3-5, absmax 1.56e-2).
//
// Round-7 = round-6 with the compile fix: __builtin_nontemporal_store needs a
// clang ext_vector_type pointer, not HIP's float4 struct.
// Theory (r6): effective read-request-volume bound ~2.5 TB/s ->
//  - 128x128 output tile (halo read amplification 1.56x -> 1.27x)
//  - 512-thread blocks: LDS 34.7KB -> 4 blocks/CU = 32 waves = 100% occ cap
//  - phase 2: one 4x8 output strip per thread, vectorized LDS reads,
//    fused vertical accumulation
//  - nontemporal output stores: don't churn L3 (keep x resident for halo hits)

#define WE0 (-0.03515625f)
#define WE1 (0.26171875f)
#define WE2 (0.87890625f)
#define WE3 (-0.10546875f)

typedef float v4f __attribute__((ext_vector_type(4)));
typedef float v2f __attribute__((ext_vector_type(2)));

__global__ __launch_bounds__(512, 8) void dwt_fused_kernel(
    const float* __restrict__ x, float* __restrict__ out)
{
    // dband physical col j holds logical dp col (tile_base + j - 2); pad 40
    // (row stride 160B) so 16B alignment is col%4-determined.
    __shared__ float db[3][36][40];   // 17280 B
    __shared__ float aaT[64][68];     // 17408 B (stride 68: 272B, 16B-aligned rows)

    const int tid = threadIdx.x;
    // bijective XCD swizzle: 1536 blocks, 192 per XCD = 12 contiguous images
    const int swz  = (blockIdx.x & 7) * 192 + (blockIdx.x >> 3);
    const int bc   = swz >> 4;         // image [0,96)
    const int tile = swz & 15;
    const int tr = tile >> 2, tc = tile & 3;   // 4x4 tiles of 128x128

    const float* xp = x + ((size_t)bc << 18);  // 512*512
    float* op       = out + ((size_t)bc << 18);

    const int bdr = tr * 32 - 2;   // logical dp row of db[.][0][.]
    const int bdc = tc * 32 - 2;

    // ---------------- Phase 1: encode into LDS ----------------
    // 36x36 = 1296 dp tasks (32x32 tile + 2 halo, clamp = edge replicate).
    for (int task = tid; task < 1296; task += 512) {
        const int i = task / 36;
        const int j = task - 36 * i;
        const int dr = min(max(bdr + i, 0), 127);
        const int dc = min(max(bdc + j, 0), 127);

        const float* src = xp + (size_t)(4 * dr) * 512 + 4 * dc;
        const v4f r0 = *reinterpret_cast<const v4f*>(src);
        const v4f r1 = *reinterpret_cast<const v4f*>(src + 512);
        const v4f r2 = *reinterpret_cast<const v4f*>(src + 1024);
        const v4f r3 = *reinterpret_cast<const v4f*>(src + 1536);

        // 2x2 Haar on each 2x2 sub-block
        const float aa00 = 0.5f * (r0.x + r0.y + r1.x + r1.y);
        const float aa01 = 0.5f * (r0.z + r0.w + r1.z + r1.w);
        const float aa10 = 0.5f * (r2.x + r2.y + r3.x + r3.y);
        const float aa11 = 0.5f * (r2.z + r2.w + r3.z + r3.w);
        const float lhs = (r0.x + r0.y - r1.x - r1.y) + (r0.z + r0.w - r1.z - r1.w)
                        + (r2.x + r2.y - r3.x - r3.y) + (r2.z + r2.w - r3.z - r3.w);
        const float hls = (r0.x - r0.y + r1.x - r1.y) + (r0.z - r0.w + r1.z - r1.w)
                        + (r2.x - r2.y + r3.x - r3.y) + (r2.z - r2.w + r3.z - r3.w);
        const float hhs = (r0.x - r0.y - r1.x + r1.y) + (r0.z - r0.w - r1.z + r1.w)
                        + (r2.x - r2.y - r3.x + r3.y) + (r2.z - r2.w - r3.z + r3.w);

        db[0][i][j] = 0.125f * lhs;   // 0.25 * (0.5 * sum)
        db[1][i][j] = 0.125f * hls;
        db[2][i][j] = 0.125f * hhs;

        if ((unsigned)(i - 2) < 32u && (unsigned)(j - 2) < 32u) {
            const int ar = 2 * (i - 2), ac = 2 * (j - 2);
            *reinterpret_cast<v2f*>(&aaT[ar][ac])     = (v2f){ aa00, aa01 };
            *reinterpret_cast<v2f*>(&aaT[ar + 1][ac]) = (v2f){ aa10, aa11 };
        }
    }

    __syncthreads();

    // ---------------- Phase 2: decode from LDS ----------------
    // Thread -> (kr in [0,32), c in [0,16)); owns dp cols kc0=2c, 2c+1
    // -> output rows 4kr..4kr+3, cols 8c..8c+7 of the tile.
    const int kr = tid >> 4;
    const int c  = tid & 15;
    const int kc0 = 2 * c;

    // U[band][i][p][par]: up-sampled band at up-row 2*KR+i, up-col 2*(kc0+p)+par
    float U[3][2][2][2];
#pragma unroll
    for (int b = 0; b < 3; ++b)
#pragma unroll
        for (int i = 0; i < 2; ++i)
#pragma unroll
            for (int p = 0; p < 2; ++p)
                U[b][i][p][0] = U[b][i][p][1] = 0.f;

    constexpr float WEv[4] = { WE0, WE1, WE2, WE3 };

#pragma unroll
    for (int b = 0; b < 3; ++b) {
#pragma unroll
        for (int r = 0; r < 5; ++r) {
            const float* rp = &db[b][kr + r][kc0];
            const v2f w01 = *reinterpret_cast<const v2f*>(rp);
            const v2f w23 = *reinterpret_cast<const v2f*>(rp + 2);
            const v2f w45 = *reinterpret_cast<const v2f*>(rp + 4);
            // horizontal cubic at dp col kc0 (p=0) and kc0+1 (p=1)
            const float he0 = WE0*w01.x + WE1*w01.y + WE2*w23.x + WE3*w23.y;
            const float ho0 = WE3*w01.y + WE2*w23.x + WE1*w23.y + WE0*w45.x;
            const float he1 = WE0*w01.y + WE1*w23.x + WE2*w23.y + WE3*w45.x;
            const float ho1 = WE3*w23.x + WE2*w23.y + WE1*w45.x + WE0*w45.y;
            // vertical accumulate: i=0 uses rows r=0..3 (WE0..WE3),
            //                      i=1 uses rows r=1..4 (WE3..WE0)
            if (r < 4) {
                const float wv = WEv[r];
                U[b][0][0][0] += wv * he0;  U[b][0][0][1] += wv * ho0;
                U[b][0][1][0] += wv * he1;  U[b][0][1][1] += wv * ho1;
            }
            if (r > 0) {
                const float wv = WEv[4 - r];
                U[b][1][0][0] += wv * he0;  U[b][1][0][1] += wv * ho0;
                U[b][1][1][0] += wv * he1;  U[b][1][1][1] += wv * ho1;
            }
        }
    }

    const v4f aar0 = *reinterpret_cast<const v4f*>(&aaT[2 * kr][4 * c]);
    const v4f aar1 = *reinterpret_cast<const v4f*>(&aaT[2 * kr + 1][4 * c]);
    const float aav[2][4] = { { aar0.x, aar0.y, aar0.z, aar0.w },
                              { aar1.x, aar1.y, aar1.z, aar1.w } };

    const int orow0 = tr * 128 + 4 * kr;
    const int ocol  = tc * 128 + 8 * c;

#pragma unroll
    for (int i = 0; i < 2; ++i) {     // up-row in pair -> out rows 2i, 2i+1
        float otop[8], obot[8];
#pragma unroll
        for (int p = 0; p < 2; ++p) {
#pragma unroll
            for (int j = 0; j < 2; ++j) {
                const float aaV = aav[i][2 * p + j];
                const float da = U[0][i][p][j];
                const float ad = U[1][i][p][j];
                const float dd = U[2][i][p][j];
                const float s1 = aaV + da, t1 = aaV - da;
                const float s2 = ad + dd,  t2 = ad - dd;
                otop[4*p + 2*j]     = 0.5f * (s1 + s2);
                otop[4*p + 2*j + 1] = 0.5f * (s1 - s2);
                obot[4*p + 2*j]     = 0.5f * (t1 + t2);
                obot[4*p + 2*j + 1] = 0.5f * (t1 - t2);
            }
        }
        float* rt = op + (size_t)(orow0 + 2 * i) * 512 + ocol;
        float* rb = rt + 512;
        __builtin_nontemporal_store((v4f){otop[0], otop[1], otop[2], otop[3]},
                                    reinterpret_cast<v4f*>(rt));
        __builtin_nontemporal_store((v4f){otop[4], otop[5], otop[6], otop[7]},
                                    reinterpret_cast<v4f*>(rt + 4));
        __builtin_nontemporal_store((v4f){obot[0], obot[1], obot[2], obot[3]},
                                    reinterpret_cast<v4f*>(rb));
        __builtin_nontemporal_store((v4f){obot[4], obot[5], obot[6], obot[7]},
                                    reinterpret_cast<v4f*>(rb + 4));
    }
}

extern "C" void kernel_launch(void* const* d_in, const int* in_sizes, int n_in,
                              void* d_out, int out_size, void* d_ws, size_t ws_size,
                              hipStream_t stream)
{
    const float* x = (const float*)d_in[0];
    float* out = (float*)d_out;
    (void)d_ws; (void)ws_size;

    const int blocks = 96 * 16;  // 1536: 96 images x 16 tiles of 128x128
    dwt_fused_kernel<<<blocks, 512, 0, stream>>>(x, out);
}